// Round 2
// baseline (238.090 us; speedup 1.0000x reference)
//
#include <hip/hip_runtime.h>
#include <hip/hip_bf16.h>

typedef __attribute__((ext_vector_type(8))) short    short8;
typedef __attribute__((ext_vector_type(4))) short    short4v;
typedef __attribute__((ext_vector_type(4))) float    float4v;
typedef __attribute__((ext_vector_type(2))) unsigned uint2v;
typedef __attribute__((ext_vector_type(4))) unsigned uint4v;

// QK^T: S^T tile = K(16x32) * Q^T(32x16), both frags row-major [pos][d]
#define MFMA_QK(A,B,C) __builtin_amdgcn_mfma_f32_16x16x32_bf16(A,B,C,0,0,0)
// PV: K=16 variant -- B-frag layout (n=lane&15, k=quad*4+jj) == QK C/D layout: zero-shuffle P feed
#define MFMA_PV(A,B,C) __builtin_amdgcn_mfma_f32_16x16x16bf16_1k(A,B,C,0,0,0)

#define N_ 4096
#define D_ 64
#define W_ 128
// 0.125 (D^-0.5) * log2(e): folded into Q so softmax uses raw exp2
#define QSCALE 0.18033688011112042f

// pack two fp32 -> bf16 pair (a in low half). +0x8000 = round-half-up: 1 perm + 2 adds
static __device__ __forceinline__ unsigned pk2(float a, float b) {
  unsigned ua = __float_as_uint(a) + 0x8000u;
  unsigned ub = __float_as_uint(b) + 0x8000u;
  return __builtin_amdgcn_perm(ub, ua, 0x07060302u);
}

static __device__ __forceinline__ void rope_sc(float rev, float& sn, float& cs) {
  float fr = rev - floorf(rev);              // v_sin/v_cos take revolutions
  sn = __builtin_amdgcn_sinf(fr);
  cs = __builtin_amdgcn_cosf(fr);
}
static __device__ __forceinline__ float invfreq_rev(int idx) {
  // 10000^(-idx/32) / (2*pi);  log2(10000)/32 = 0.41524101186092034
  return exp2f(-0.41524101186092034f * (float)idx) * 0.15915494309189535f;
}

// cos/sin table: [N][32] each, fp32. 1 MB total, shared by all 64 heads -> L2-resident.
__global__ void gen_tab(float* __restrict__ cosT, float* __restrict__ sinT) {
  int i = blockIdx.x * 256 + threadIdx.x;    // 4096*32 elements exactly
  int n = i >> 5, d = i & 31;
  float sn, cs;
  rope_sc((float)n * invfreq_rev(d), sn, cs);
  cosT[i] = cs; sinT[i] = sn;
}

template<bool TAB>
__global__ __launch_bounds__(256, 2)
void la_fused(const float* __restrict__ qg, const float* __restrict__ kg,
              const float* __restrict__ vg, float* __restrict__ outg,
              const float* __restrict__ cosT, const float* __restrict__ sinT)
{
  // K rows stride 72 shorts (144B): b128 frag reads spread over all 32 banks (8-cyc optimal)
  __shared__ __attribute__((aligned(16))) short Kl[256][72];
  // V^T as [j-chunk][d padded 64->68][4 j's]: b64 reads AND (dd+lane)-rotated b64 writes
  // both hit 4-way/32-bank = optimal
  __shared__ __attribute__((aligned(16))) short Vt[64][68][4];

  const int blk  = blockIdx.x;
  const int w    = blk & 31;
  const int bh   = blk >> 5;
  const int base = bh * (N_ * D_);
  const int tid  = threadIdx.x;
  const int lane = tid & 63;
  const int wv   = tid >> 6;
  const int il   = lane & 15;
  const int qd   = lane >> 4;

  // ---------------- stage K (RoPE'd bf16) ----------------
  {
    const float* kb = kg + base;
#pragma unroll
    for (int it = 0; it < 8; ++it) {
      int tau = it * 256 + tid;
      int j   = tau >> 3;            // key row 0..255
      int d0  = (tau & 7) << 2;      // 0..28
      int g   = w * W_ - W_ + j;
      uint2v w0, w1;
      if (g < 0) {                   // look_around pads AFTER rope with exact -1.0
        unsigned m1 = pk2(-1.0f, -1.0f);
        w0 = uint2v{m1, m1}; w1 = w0;
      } else {
        float4v a = *(const float4v*)(kb + g * D_ + d0);
        float4v b = *(const float4v*)(kb + g * D_ + d0 + 32);
        float4v cs, sn;
        if constexpr (TAB) {
          cs = *(const float4v*)(cosT + g * 32 + d0);
          sn = *(const float4v*)(sinT + g * 32 + d0);
        } else {
          const float t = (float)g;
#pragma unroll
          for (int dd = 0; dd < 4; ++dd) { float s_, c_; rope_sc(t * invfreq_rev(d0 + dd), s_, c_); sn[dd]=s_; cs[dd]=c_; }
        }
        float lo[4], hi[4];
#pragma unroll
        for (int dd = 0; dd < 4; ++dd) {
          lo[dd] = a[dd] * cs[dd] - b[dd] * sn[dd];
          hi[dd] = b[dd] * cs[dd] + a[dd] * sn[dd];
        }
        w0 = uint2v{ pk2(lo[0], lo[1]), pk2(lo[2], lo[3]) };
        w1 = uint2v{ pk2(hi[0], hi[1]), pk2(hi[2], hi[3]) };
      }
      *(uint2v*)&Kl[j][d0]      = w0;
      *(uint2v*)&Kl[j][d0 + 32] = w1;
    }
  }

  // ---------------- stage V^T via 4x4 in-register block transpose ----------------
  {
    const float* vb = vg + base;
    const int m  = tid & 15;
    const int d0 = m << 2;
#pragma unroll
    for (int pv = 0; pv < 4; ++pv) {
      int j0 = ((tid >> 4) + pv * 16) << 2;      // row block (multiple of 4)
      int g0 = w * W_ - W_ + j0;
      float vv[4][4];
      if (g0 < 0) {
#pragma unroll
        for (int rr = 0; rr < 4; ++rr)
#pragma unroll
          for (int cc = 0; cc < 4; ++cc) vv[rr][cc] = -1.0f;
      } else {
#pragma unroll
        for (int rr = 0; rr < 4; ++rr) {
          float4v r = *(const float4v*)(vb + (g0 + rr) * D_ + d0);
          vv[rr][0]=r[0]; vv[rr][1]=r[1]; vv[rr][2]=r[2]; vv[rr][3]=r[3];
        }
      }
      const int chunk = j0 >> 2;
#pragma unroll
      for (int dd = 0; dd < 4; ++dd) {
        int cc = (dd + m) & 3;                    // lane-rotated write order: spreads banks
        uint2v wvv = uint2v{ pk2(vv[0][cc], vv[1][cc]), pk2(vv[2][cc], vv[3][cc]) };
        *(uint2v*)&Vt[chunk][d0 + cc][0] = wvv;
      }
    }
  }

  // ---------------- Q fragments (RoPE'd, pre-scaled) -- no LDS dep, before barrier ----
  short8 qf[2][2];
#pragma unroll
  for (int ii = 0; ii < 2; ++ii) {
    const int n = w * W_ + wv * 32 + ii * 16 + il;
    const float* qr = qg + base + n * D_ + qd * 8;
    float4v x0 = *(const float4v*)(qr);
    float4v x1 = *(const float4v*)(qr + 4);
    float4v y0 = *(const float4v*)(qr + 32);
    float4v y1 = *(const float4v*)(qr + 36);
    float4v c0, c1, s0, s1;
    if constexpr (TAB) {
      c0 = *(const float4v*)(cosT + n * 32 + qd * 8);
      c1 = *(const float4v*)(cosT + n * 32 + qd * 8 + 4);
      s0 = *(const float4v*)(sinT + n * 32 + qd * 8);
      s1 = *(const float4v*)(sinT + n * 32 + qd * 8 + 4);
    } else {
      const float t = (float)n;
#pragma unroll
      for (int dd = 0; dd < 4; ++dd) {
        float s_, c_;
        rope_sc(t * invfreq_rev(qd * 8 + dd), s_, c_);     s0[dd]=s_; c0[dd]=c_;
        rope_sc(t * invfreq_rev(qd * 8 + 4 + dd), s_, c_); s1[dd]=s_; c1[dd]=c_;
      }
    }
    float lo[8], hi[8];
#pragma unroll
    for (int jj = 0; jj < 8; ++jj) {
      float xx = (jj < 4) ? x0[jj & 3] : x1[jj & 3];
      float yy = (jj < 4) ? y0[jj & 3] : y1[jj & 3];
      float cs = (jj < 4) ? c0[jj & 3] : c1[jj & 3];
      float sn = (jj < 4) ? s0[jj & 3] : s1[jj & 3];
      float xs = xx * QSCALE, ys = yy * QSCALE;
      lo[jj] = xs * cs - ys * sn;
      hi[jj] = ys * cs + xs * sn;
    }
    uint4v pa = uint4v{ pk2(lo[0],lo[1]), pk2(lo[2],lo[3]), pk2(lo[4],lo[5]), pk2(lo[6],lo[7]) };
    uint4v pb = uint4v{ pk2(hi[0],hi[1]), pk2(hi[2],hi[3]), pk2(hi[4],hi[5]), pk2(hi[6],hi[7]) };
    qf[ii][0] = __builtin_bit_cast(short8, pa);
    qf[ii][1] = __builtin_bit_cast(short8, pb);
  }

  __syncthreads();

  // ---------------- S^T = K * Q^T ----------------
  float4v S[2][16];
#pragma unroll
  for (int ii = 0; ii < 2; ++ii)
#pragma unroll
    for (int t = 0; t < 16; ++t) { float4v z = {0.f,0.f,0.f,0.f}; S[ii][t] = z; }

#pragma unroll
  for (int t = 0; t < 16; ++t) {
    short8 a0 = *(const short8*)&Kl[t * 16 + il][qd * 8];
    short8 a1 = *(const short8*)&Kl[t * 16 + il][32 + qd * 8];
#pragma unroll
    for (int ii = 0; ii < 2; ++ii) {
      S[ii][t] = MFMA_QK(a0, qf[ii][0], S[ii][t]);
      S[ii][t] = MFMA_QK(a1, qf[ii][1], S[ii][t]);
    }
  }

  // ---------------- softmax (base-2 domain; scale pre-folded into Q) ----------------
  short4v P[2][16];
  float   invsum[2];
#pragma unroll
  for (int ii = 0; ii < 2; ++ii) {
    const int rw   = wv * 32 + ii * 16 + il;
    const int jcap = rw + 128;
    float mx = -1.0e30f;
#pragma unroll
    for (int t = 0; t < 16; ++t) {
      // tiles fully below the causal boundary for every lane of this wave need no mask
      bool maybe = (t * 16 + 15) > (wv * 32 + ii * 16 + 128);
#pragma unroll
      for (int r = 0; r < 4; ++r) {
        float s = S[ii][t][r];
        if (maybe) { int j = t * 16 + qd * 4 + r; if (j > jcap) s = -1.0e30f; }
        S[ii][t][r] = s;
        mx = fmaxf(mx, s);
      }
    }
    mx = fmaxf(mx, __shfl_xor(mx, 16));
    mx = fmaxf(mx, __shfl_xor(mx, 32));
    float sum = 0.0f;
#pragma unroll
    for (int t = 0; t < 16; ++t)
#pragma unroll
      for (int r = 0; r < 4; ++r) {
        float p = __builtin_amdgcn_exp2f(S[ii][t][r] - mx);
        S[ii][t][r] = p;
        sum += p;
      }
    sum += __shfl_xor(sum, 16);
    sum += __shfl_xor(sum, 32);
    invsum[ii] = __builtin_amdgcn_rcpf(sum);
#pragma unroll
    for (int t = 0; t < 16; ++t) {
      uint2v pw = uint2v{ pk2(S[ii][t][0], S[ii][t][1]), pk2(S[ii][t][2], S[ii][t][3]) };
      P[ii][t] = __builtin_bit_cast(short4v, pw);
    }
  }

  // ---------------- O^T = V^T * P^T ----------------
  float4v O[2][4];
#pragma unroll
  for (int ii = 0; ii < 2; ++ii)
#pragma unroll
    for (int dt = 0; dt < 4; ++dt) { float4v z = {0.f,0.f,0.f,0.f}; O[ii][dt] = z; }

#pragma unroll
  for (int c = 0; c < 16; ++c) {
    short4v af[4];
#pragma unroll
    for (int dt = 0; dt < 4; ++dt)   // V^T[d=dt*16+il][j=c*16+qd*4 ..+3]
      af[dt] = *(const short4v*)&Vt[c * 4 + qd][dt * 16 + il][0];
#pragma unroll
    for (int dt = 0; dt < 4; ++dt) {
      O[0][dt] = MFMA_PV(af[dt], P[0][c], O[0][dt]);
      O[1][dt] = MFMA_PV(af[dt], P[1][c], O[1][dt]);
    }
  }

  // ---------------- epilogue ----------------
#pragma unroll
  for (int ii = 0; ii < 2; ++ii) {
    const int n = w * W_ + wv * 32 + ii * 16 + il;
    float* op = outg + base + n * D_;
    const float inv = invsum[ii];
#pragma unroll
    for (int dt = 0; dt < 4; ++dt) {
      float4v o = O[ii][dt];
      o[0] *= inv; o[1] *= inv; o[2] *= inv; o[3] *= inv;
      *(float4v*)(op + dt * 16 + qd * 4) = o;
    }
  }
}

extern "C" void kernel_launch(void* const* d_in, const int* in_sizes, int n_in,
                              void* d_out, int out_size, void* d_ws, size_t ws_size,
                              hipStream_t stream)
{
  const float* q = (const float*)d_in[0];
  const float* k = (const float*)d_in[1];
  const float* v = (const float*)d_in[2];
  float* out = (float*)d_out;
  const size_t tabBytes = (size_t)N_ * 32 * 2 * sizeof(float);   // 1 MB
  if (ws_size >= tabBytes) {
    float* cosT = (float*)d_ws;
    float* sinT = cosT + N_ * 32;
    gen_tab<<<dim3(512), dim3(256), 0, stream>>>(cosT, sinT);
    la_fused<true><<<dim3(64 * 32), dim3(256), 0, stream>>>(q, k, v, out, cosT, sinT);
  } else {
    la_fused<false><<<dim3(64 * 32), dim3(256), 0, stream>>>(q, k, v, out, nullptr, nullptr);
  }
}